// Round 4
// baseline (498.851 us; speedup 1.0000x reference)
//
#include <hip/hip_runtime.h>
#include <stdint.h>

#define LDIM 512
#define LLTOT 262144            // 512*512
#define EPSV 1e-5f

typedef short bf16x8 __attribute__((ext_vector_type(8)));
typedef float f32x4 __attribute__((ext_vector_type(4)));
typedef __attribute__((address_space(1))) unsigned as1_u32;
typedef __attribute__((address_space(3))) unsigned as3_u32;

__device__ __forceinline__ void stage16(const void* g, void* l) {
  __builtin_amdgcn_global_load_lds((as1_u32*)g, (as3_u32*)l, 16, 0, 0);
}

__device__ __forceinline__ unsigned short f2bf(float f) {
  union { float f; unsigned u; } v; v.f = f;
  unsigned r = v.u + 0x7FFFu + ((v.u >> 16) & 1u);   // RNE
  return (unsigned short)(r >> 16);
}
__device__ __forceinline__ float bf2f(unsigned short h) {
  union { unsigned u; float f; } v; v.u = ((unsigned)h) << 16;
  return v.f;
}
// packed bf16 convert: lo -> [15:0], hi -> [31:16], RNE
__device__ __forceinline__ unsigned cvtpk(float lo, float hi) {
  unsigned r;
  asm("v_cvt_pk_bf16_f32 %0, %1, %2" : "=v"(r) : "v"(lo), "v"(hi));
  return r;
}
__device__ __forceinline__ float sigm(float x) { return 1.0f / (1.0f + __expf(-x)); }

// a/b layout v3 (write-contiguous, read-gatherable):
//   element (i, k, c) lives at  i*131072 + (k>>5)*8192 + c*64 + (k&31)*2
// -> a k_proj block (one i, 128 consecutive k, all 128 c) writes ONE
//    contiguous 32 KB span.
// -> an einsum MFMA fragment (fixed c, 16 i, one 32-k chunk) = 16 x 64B rows
//    at 128 KB stride; global_load_lds's PER-LANE global source gathers it in
//    one instr (4 lanes per 64B row), landing in LDS in the fragment cell
//    order [irem][(k&31)*2].  LDS-side layout unchanged.
//
// OCCUPANCY NOTE (round 4): LDS caps k_proj at 4 blocks/CU and
// k_einsum/k_out at 3 blocks/CU.  Without a min-waves hint the allocator
// targeted 8 waves/SIMD (64-VGPR budget) -- unreachable -- and spilled /
// re-fetched the resident weight fragments every rg iteration.
// __launch_bounds__(256, N) aligns the VGPR budget with the LDS cap:
// k_proj (256,4) -> 128 VGPRs (weights wg+wp = 64 stay resident);
// k_einsum/k_out (256,3) -> ~170 VGPRs (acc[4][4]=64 resident).

// ---------------------------------------------------------------------------
// K0: weights fp32 [c][o] -> bf16 transposed [o][c].  Order: ga,pa,gb,pb,go,po
// ---------------------------------------------------------------------------
__global__ void k_prep(const float* __restrict__ Wpa, const float* __restrict__ Wga,
                       const float* __restrict__ Wpb, const float* __restrict__ Wgb,
                       const float* __restrict__ Wgo, const float* __restrict__ Wpo,
                       unsigned short* __restrict__ Wt) {
  int t = blockIdx.x * blockDim.x + threadIdx.x;     // 0..98303
  int mat = t >> 14;
  int rem = t & 16383;
  int o = rem >> 7;
  int c = rem & 127;
  const float* src;
  switch (mat) {
    case 0: src = Wga; break;
    case 1: src = Wpa; break;
    case 2: src = Wgb; break;
    case 3: src = Wpb; break;
    case 4: src = Wgo; break;
    default: src = Wpo; break;
  }
  Wt[mat * 16384 + o * 128 + c] = f2bf(src[c * 128 + o]);
}

// ---------------------------------------------------------------------------
// K1 (fused LN + projections), weights-resident.  Per block: 128 flat positions
// (one z-row i, 128 consecutive k).  a/b stored in v3 layout.  Barrier-free
// after the LN sync.
// ---------------------------------------------------------------------------
__global__ __launch_bounds__(256, 4) void k_proj(const float* __restrict__ z,
                                                 const float* __restrict__ lnw,
                                                 const float* __restrict__ lnb,
                                                 const unsigned short* __restrict__ Wt,
                                                 const int* __restrict__ maskp,
                                                 unsigned short* __restrict__ a_f,
                                                 unsigned short* __restrict__ b_f,
                                                 unsigned short* __restrict__ gout) {
  __shared__ __align__(16) unsigned char zbuf[128 * 272];   // rows padded 256->272B
  __shared__ float maskf[128];
  const int t = threadIdx.x;
  const int bid = blockIdx.x;
  const long r0 = (long)bid * 128;
  const int w = t >> 6, lane = t & 63;
  const int mn = lane & 15, q4 = lane >> 4;
  // layout constants for this block
  const int k0 = (bid & 3) * 128;          // first global k
  const long ibase = (long)(bid >> 2) * 131072;   // i * 128KB

  if (t < 128) maskf[t] = (float)maskp[r0 + t];

  // fused input LayerNorm: wave w owns rows w*32..w*32+31; 4 rows/iter,
  // lane holds 8 channels of one row (32B load); reduce over 16 lanes.
  {
    const int sub = lane >> 4, c16 = lane & 15;
    const float4 lw0 = ((const float4*)lnw)[c16 * 2];
    const float4 lw1 = ((const float4*)lnw)[c16 * 2 + 1];
    const float4 lb0 = ((const float4*)lnb)[c16 * 2];
    const float4 lb1 = ((const float4*)lnb)[c16 * 2 + 1];
#pragma unroll 2
    for (int rr = 0; rr < 8; ++rr) {
      const int row = w * 32 + rr * 4 + sub;
      const float4* zr = (const float4*)(z + (r0 + row) * 128);
      float4 v0 = zr[c16 * 2], v1 = zr[c16 * 2 + 1];
      float s = ((v0.x + v0.y) + (v0.z + v0.w)) + ((v1.x + v1.y) + (v1.z + v1.w));
      float q = v0.x * v0.x + v0.y * v0.y + v0.z * v0.z + v0.w * v0.w +
                v1.x * v1.x + v1.y * v1.y + v1.z * v1.z + v1.w * v1.w;
#pragma unroll
      for (int off = 8; off; off >>= 1) { s += __shfl_xor(s, off); q += __shfl_xor(q, off); }
      float mu = s * (1.0f / 128.0f);
      float rs = rsqrtf(q * (1.0f / 128.0f) - mu * mu + EPSV);
      uint4 o;
      o.x = cvtpk((v0.x - mu) * rs * lw0.x + lb0.x, (v0.y - mu) * rs * lw0.y + lb0.y);
      o.y = cvtpk((v0.z - mu) * rs * lw0.z + lb0.z, (v0.w - mu) * rs * lw0.w + lb0.w);
      o.z = cvtpk((v1.x - mu) * rs * lw1.x + lb1.x, (v1.y - mu) * rs * lw1.y + lb1.y);
      o.w = cvtpk((v1.z - mu) * rs * lw1.z + lb1.z, (v1.w - mu) * rs * lw1.w + lb1.w);
      *(uint4*)(&zbuf[row * 272 + c16 * 16]) = o;
    }
  }
  __syncthreads();
  // no further barriers: zbuf is read-only from here; waves free-run.

  // phases p=0 (a), p=1 (b): gate+proj weights resident in VGPRs
#pragma unroll 1
  for (int p = 0; p < 2; ++p) {
    const unsigned short* Wg = Wt + (p * 2) * 16384;
    const unsigned short* Wp = Wt + (p * 2 + 1) * 16384;
    unsigned short* dst = p ? b_f : a_f;
    bf16x8 wg[2][4], wp[2][4];
#pragma unroll
    for (int ntl = 0; ntl < 2; ++ntl)
#pragma unroll
      for (int kk = 0; kk < 4; ++kk) {
        const int o = (w * 2 + ntl) * 16 + mn;
        wg[ntl][kk] = *(const bf16x8*)(Wg + o * 128 + kk * 32 + q4 * 8);
        wp[ntl][kk] = *(const bf16x8*)(Wp + o * 128 + kk * 32 + q4 * 8);
      }
#pragma unroll 1
    for (int rg = 0; rg < 8; ++rg) {
      bf16x8 afr[4];
#pragma unroll
      for (int kk = 0; kk < 4; ++kk)
        afr[kk] = *(const bf16x8*)(&zbuf[(rg * 16 + mn) * 272 + kk * 64 + q4 * 16]);
      f32x4 aG[2] = {{0.f,0.f,0.f,0.f},{0.f,0.f,0.f,0.f}};
      f32x4 aP[2] = {{0.f,0.f,0.f,0.f},{0.f,0.f,0.f,0.f}};
#pragma unroll
      for (int kk = 0; kk < 4; ++kk)
#pragma unroll
        for (int ntl = 0; ntl < 2; ++ntl) {
          aG[ntl] = __builtin_amdgcn_mfma_f32_16x16x32_bf16(afr[kk], wg[ntl][kk], aG[ntl], 0, 0, 0);
          aP[ntl] = __builtin_amdgcn_mfma_f32_16x16x32_bf16(afr[kk], wp[ntl][kk], aP[ntl], 0, 0, 0);
        }
      const int rowb = rg * 16 + q4 * 4;        // k-offset within block (4 consec)
      const int kpos = k0 + rowb;               // global k of first element
      // v3 address: ibase + (kpos>>5)*8192 + c*64 + (kpos&31)*2
      char* dst0 = (char*)dst + ibase + (kpos >> 5) * 8192 + (kpos & 31) * 2;
#pragma unroll
      for (int ntl = 0; ntl < 2; ++ntl) {
        const int c = (w * 2 + ntl) * 16 + mn;
        float e0 = sigm(aG[ntl][0]) * aP[ntl][0] * maskf[rowb + 0];
        float e1 = sigm(aG[ntl][1]) * aP[ntl][1] * maskf[rowb + 1];
        float e2 = sigm(aG[ntl][2]) * aP[ntl][2] * maskf[rowb + 2];
        float e3 = sigm(aG[ntl][3]) * aP[ntl][3] * maskf[rowb + 3];
        uint2 pk;
        pk.x = cvtpk(e0, e1);
        pk.y = cvtpk(e2, e3);
        *(uint2*)(dst0 + c * 64) = pk;
      }
    }
  }

  {  // g phase: g = sigmoid(zln @ Wgo) -> gout[row][c] (block region is 64KB
     // contiguous; 2B stores merge in L2)
    const unsigned short* Wgp = Wt + 4 * 16384;
    bf16x8 wg[2][4];
#pragma unroll
    for (int ntl = 0; ntl < 2; ++ntl)
#pragma unroll
      for (int kk = 0; kk < 4; ++kk)
        wg[ntl][kk] = *(const bf16x8*)(Wgp + ((w * 2 + ntl) * 16 + mn) * 128 + kk * 32 + q4 * 8);
#pragma unroll 1
    for (int rg = 0; rg < 8; ++rg) {
      bf16x8 afr[4];
#pragma unroll
      for (int kk = 0; kk < 4; ++kk)
        afr[kk] = *(const bf16x8*)(&zbuf[(rg * 16 + mn) * 272 + kk * 64 + q4 * 16]);
      f32x4 aG[2] = {{0.f,0.f,0.f,0.f},{0.f,0.f,0.f,0.f}};
#pragma unroll
      for (int kk = 0; kk < 4; ++kk)
#pragma unroll
        for (int ntl = 0; ntl < 2; ++ntl)
          aG[ntl] = __builtin_amdgcn_mfma_f32_16x16x32_bf16(afr[kk], wg[ntl][kk], aG[ntl], 0, 0, 0);
      const int rowb = rg * 16 + q4 * 4;
#pragma unroll
      for (int ntl = 0; ntl < 2; ++ntl) {
        const int c = (w * 2 + ntl) * 16 + mn;
        unsigned u01 = cvtpk(sigm(aG[ntl][0]), sigm(aG[ntl][1]));
        unsigned u23 = cvtpk(sigm(aG[ntl][2]), sigm(aG[ntl][3]));
        gout[(r0 + rowb + 0) * 128 + c] = (unsigned short)u01;
        gout[(r0 + rowb + 1) * 128 + c] = (unsigned short)(u01 >> 16);
        gout[(r0 + rowb + 2) * 128 + c] = (unsigned short)u23;
        gout[(r0 + rowb + 3) * 128 + c] = (unsigned short)(u23 >> 16);
      }
    }
  }
}

// ---------------------------------------------------------------------------
// K3: per-channel GEMM  m_c = a_c @ b_c^T from v3-layout operands.
// 3-buffer counted-vmcnt pipeline.  Fragment staging: one stage16 per frag,
// PER-LANE gather (lane l -> row i = f*16 + (l>>2), byte (l&3)*16 of the
// (i,kc,ch) 64B row) -> LDS lands lane-linear in the fragment cell order, so
// ds_read/MFMA mapping is unchanged.  A frags reused x4 by same-XCD siblings.
// ---------------------------------------------------------------------------
__global__ __launch_bounds__(256, 3) void k_einsum(const unsigned short* __restrict__ af_g,
                                                   const unsigned short* __restrict__ bf_g,
                                                   unsigned short* __restrict__ m_t) {
  __shared__ __align__(16) unsigned char shm[49152];  // 3 x 16KB stage; epilogue reuses
  const int t = threadIdx.x;
  const int w = t >> 6, lane = t & 63;
  const int bid = blockIdx.x;
  const int xcd = bid & 7;               // round-robin bid%8 -> XCD
  const int j = bid >> 3;
  const int ch = xcd * 16 + (j >> 4);    // 16 channels per XCD
  const int tile = j & 15;
  const int ti = tile >> 2, tj = tile & 3;
  const int wr = w >> 1, wc = w & 1;
  const int mn = lane & 15, q4 = lane >> 4;
  const int loff = (mn * 4 + q4) * 16;   // cell order: (i&15)*4 + k-subchunk

  // per-lane gather component: row (l>>2) of the 16-row frag, 16B piece (l&3)
  const long lanepart = (long)(lane >> 2) * 131072 + (lane & 3) * 16 + ch * 64;

  // wave w stages fragments f = w*4 .. w*4+3  (f<8: A frag ti*8+f, else B frag)
  const char* gsrc[4];
#pragma unroll
  for (int u = 0; u < 4; ++u) {
    const int f = w * 4 + u;
    gsrc[u] = (f < 8)
        ? (const char*)af_g + (long)(ti * 8 + f) * 16 * 131072 + lanepart
        : (const char*)bf_g + (long)(tj * 8 + (f - 8)) * 16 * 131072 + lanepart;
  }

  f32x4 acc[4][4];
#pragma unroll
  for (int i = 0; i < 4; ++i)
#pragma unroll
    for (int jj = 0; jj < 4; ++jj) acc[i][jj] = (f32x4){0.f, 0.f, 0.f, 0.f};

#define STAGE(q, k32)                                                          \
  {                                                                            \
    _Pragma("unroll")                                                          \
    for (int u = 0; u < 4; ++u)                                                \
      stage16(gsrc[u] + (long)(k32) * 8192,                                    \
              &shm[(q) * 16384 + (w * 4 + u) * 1024]);                         \
  }

  STAGE(0, 0)
  STAGE(1, 1)
#pragma unroll 1
  for (int k32 = 0; k32 < 16; ++k32) {
    if (k32 < 15) {
      // buf k resident when only the newest 4 (buf k+1's) remain outstanding
      asm volatile("s_waitcnt vmcnt(4)\n\ts_barrier" ::: "memory");
    } else {
      asm volatile("s_waitcnt vmcnt(0)\n\ts_barrier" ::: "memory");
    }
    if (k32 + 2 < 16) STAGE((k32 + 2) % 3, k32 + 2)   // overwrite buf (k-1): safe
    const int cb = (k32 % 3) * 16384;
    bf16x8 afr[4], bfr[4];
#pragma unroll
    for (int mt = 0; mt < 4; ++mt)
      afr[mt] = *(const bf16x8*)(&shm[cb + (wr * 4 + mt) * 1024 + loff]);
#pragma unroll
    for (int nt = 0; nt < 4; ++nt)
      bfr[nt] = *(const bf16x8*)(&shm[cb + 8192 + (wc * 4 + nt) * 1024 + loff]);
#pragma unroll
    for (int mt = 0; mt < 4; ++mt)
#pragma unroll
      for (int nt = 0; nt < 4; ++nt)
        acc[mt][nt] = __builtin_amdgcn_mfma_f32_16x16x32_bf16(
            afr[mt], bfr[nt], acc[mt][nt], 0, 0, 0);
  }
#undef STAGE
  __syncthreads();   // all waves done reading stage buffers before eb reuse

  // epilogue: per-wave LDS bounce (rows padded to 144B), coalesced bf16 store.
  unsigned char* eb = shm + w * 9216;
#pragma unroll
  for (int mt = 0; mt < 4; ++mt)
#pragma unroll
    for (int nt = 0; nt < 4; ++nt) {
      const int rlb = mt * 16 + q4 * 4;
      const int cl = nt * 16 + mn;
      unsigned u01 = cvtpk(acc[mt][nt][0], acc[mt][nt][1]);
      unsigned u23 = cvtpk(acc[mt][nt][2], acc[mt][nt][3]);
      *(unsigned short*)(&eb[(rlb + 0) * 144 + cl * 2]) = (unsigned short)u01;
      *(unsigned short*)(&eb[(rlb + 1) * 144 + cl * 2]) = (unsigned short)(u01 >> 16);
      *(unsigned short*)(&eb[(rlb + 2) * 144 + cl * 2]) = (unsigned short)u23;
      *(unsigned short*)(&eb[(rlb + 3) * 144 + cl * 2]) = (unsigned short)(u23 >> 16);
    }
  char* Mg = (char*)m_t + (long)ch * 524288 +
             (long)(ti * 128 + wr * 64) * 1024 + (tj * 128 + wc * 64) * 2;
#pragma unroll
  for (int it = 0; it < 8; ++it) {
    int rl = it * 8 + (lane >> 3), cc = lane & 7;
    *(int4*)(Mg + (long)rl * 1024 + cc * 16) = *(const int4*)(&eb[rl * 144 + cc * 16]);
  }
}

// ---------------------------------------------------------------------------
// K4: per 64-row tile: LN(m) over c, m_ln @ Wpo, * g * mask -> dz fp32
// ---------------------------------------------------------------------------
__global__ __launch_bounds__(256, 3) void k_out(const unsigned short* __restrict__ m_t,
                                                const unsigned short* __restrict__ gbuf,
                                                const unsigned short* __restrict__ Wt,
                                                const int* __restrict__ maskp,
                                                const float* __restrict__ lnw,
                                                const float* __restrict__ lnb,
                                                float* __restrict__ out) {
  __shared__ unsigned char mln[64 * 272];   // [row][c] bf16, padded rows
  __shared__ float obuf[64 * 132];          // [row][c] fp32, padded rows
  __shared__ float lw[128], lb[128], mk[64];
  const int t = threadIdx.x;
  const long r0 = (long)blockIdx.x * 64;

  // stage + transpose m tile: m_t[c][r0+..] -> mln[row][c], e-rotated
#pragma unroll
  for (int it = 0; it < 4; ++it) {
    int chunk = it * 256 + t;
    int c = chunk >> 3, cc = chunk & 7;
    int4 rv = *(const int4*)((const char*)m_t + (long)c * 524288 + r0 * 2 + cc * 16);
    const unsigned short* rp = (const unsigned short*)&rv;
#pragma unroll
    for (int e = 0; e < 8; ++e) {
      int er = (e + cc) & 7;   // rotate: rows mod 8 distinct across lanes
      *(unsigned short*)(&mln[(cc * 8 + er) * 272 + c * 2]) = rp[er];
    }
  }
  if (t < 128) { lw[t] = lnw[t]; lb[t] = lnb[t]; }
  if (t < 64) mk[t] = (float)maskp[r0 + t];
  __syncthreads();

  {  // LayerNorm over c: 4 threads per row; write m_ln back in place (bf16)
    int row = t >> 2, part = t & 3;
    float xv[32];
    float s = 0.f, q = 0.f;
#pragma unroll
    for (int jj = 0; jj < 16; ++jj) {
      unsigned u = *(const unsigned*)(&mln[row * 272 + part * 64 + jj * 4]);
      float x0 = bf2f((unsigned short)(u & 0xffff));
      float x1 = bf2f((unsigned short)(u >> 16));
      xv[2 * jj] = x0; xv[2 * jj + 1] = x1;
      s += x0 + x1; q += x0 * x0 + x1 * x1;
    }
    s += __shfl_xor(s, 1); q += __shfl_xor(q, 1);
    s += __shfl_xor(s, 2); q += __shfl_xor(q, 2);
    float mu = s * (1.f / 128.f);
    float var = q * (1.f / 128.f) - mu * mu;
    float rs = rsqrtf(var + EPSV);
#pragma unroll
    for (int jj = 0; jj < 16; ++jj) {
      int c = part * 32 + 2 * jj;
      unsigned pk = cvtpk((xv[2 * jj] - mu) * rs * lw[c] + lb[c],
                          (xv[2 * jj + 1] - mu) * rs * lw[c + 1] + lb[c + 1]);
      *(unsigned*)(&mln[row * 272 + c * 2]) = pk;
    }
  }
  __syncthreads();

  // GEMM: m_ln @ Wpo -> obuf (raw acc)
  const int w = t >> 6, lane = t & 63;
  const int mn = lane & 15, q4 = lane >> 4;
  bf16x8 afr[4];
#pragma unroll
  for (int kk = 0; kk < 4; ++kk)
    afr[kk] = *(const bf16x8*)(&mln[(w * 16 + mn) * 272 + kk * 64 + q4 * 16]);
  const unsigned short* Wp = Wt + 5 * 16384;
#pragma unroll 1
  for (int nt = 0; nt < 8; ++nt) {
    f32x4 acc = {0.f, 0.f, 0.f, 0.f};
#pragma unroll
    for (int kk = 0; kk < 4; ++kk) {
      bf16x8 bfr = *(const bf16x8*)(Wp + (nt * 16 + mn) * 128 + kk * 32 + q4 * 8);
      acc = __builtin_amdgcn_mfma_f32_16x16x32_bf16(afr[kk], bfr, acc, 0, 0, 0);
    }
    const int cl = nt * 16 + mn;
#pragma unroll
    for (int r = 0; r < 4; ++r)
      obuf[(w * 16 + q4 * 4 + r) * 132 + cl] = acc[r];
  }
  __syncthreads();

  // out = obuf * g * mask (coalesced; g read as bf16x4 chunks)
#pragma unroll
  for (int it = 0; it < 8; ++it) {
    int chunk = it * 256 + t;
    int row = chunk >> 5, cc = chunk & 31;
    float4 v = *(const float4*)(&obuf[row * 132 + cc * 4]);
    uint2 gp = *(const uint2*)((const char*)gbuf + (r0 + row) * 256 + cc * 8);
    float mval = mk[row];
    v.x *= bf2f((unsigned short)(gp.x & 0xffff)) * mval;
    v.y *= bf2f((unsigned short)(gp.x >> 16)) * mval;
    v.z *= bf2f((unsigned short)(gp.y & 0xffff)) * mval;
    v.w *= bf2f((unsigned short)(gp.y >> 16)) * mval;
    *(float4*)(out + (r0 + row) * 128 + cc * 4) = v;
  }
}

// ---------------------------------------------------------------------------
extern "C" void kernel_launch(void* const* d_in, const int* in_sizes, int n_in,
                              void* d_out, int out_size, void* d_ws, size_t ws_size,
                              hipStream_t stream) {
  const float* z    = (const float*)d_in[0];
  const int* maskp  = (const int*)d_in[1];
  const float* lniw = (const float*)d_in[2];
  const float* lnib = (const float*)d_in[3];
  const float* lnow = (const float*)d_in[4];
  const float* lnob = (const float*)d_in[5];
  const float* Wpa  = (const float*)d_in[6];
  const float* Wga  = (const float*)d_in[7];
  const float* Wpb  = (const float*)d_in[8];
  const float* Wgb  = (const float*)d_in[9];
  const float* Wgo  = (const float*)d_in[10];
  const float* Wpo  = (const float*)d_in[11];
  float* out = (float*)d_out;

  char* ws = (char*)d_ws;
  unsigned short* a_f = (unsigned short*)(ws);                 // bf16 v3 layout, 64 MiB
  unsigned short* b_f = (unsigned short*)(ws + 67108864);      // bf16 v3 layout
  unsigned short* g   = (unsigned short*)(ws + 134217728);     // bf16 [262144][128]
  unsigned short* m_t = (unsigned short*)(ws + 201326592);     // bf16 [128][262144]
  unsigned short* Wt  = (unsigned short*)(ws + 268435456);     // 6 x [128][128] bf16

  k_prep<<<384, 256, 0, stream>>>(Wpa, Wga, Wpb, Wgb, Wgo, Wpo, Wt);
  k_proj<<<2048, 256, 0, stream>>>(z, lniw, lnib, Wt, maskp, a_f, b_f, g);
  k_einsum<<<2048, 256, 0, stream>>>(a_f, b_f, m_t);
  k_out<<<4096, 256, 0, stream>>>(m_t, g, Wt, maskp, lnow, lnob, out);
}

// Round 5
// 485.284 us; speedup vs baseline: 1.0280x; 1.0280x over previous
//
#include <hip/hip_runtime.h>
#include <stdint.h>

#define LDIM 512
#define LLTOT 262144            // 512*512
#define EPSV 1e-5f

typedef short bf16x8 __attribute__((ext_vector_type(8)));
typedef float f32x4 __attribute__((ext_vector_type(4)));
typedef __attribute__((address_space(1))) unsigned as1_u32;
typedef __attribute__((address_space(3))) unsigned as3_u32;

__device__ __forceinline__ void stage16(const void* g, void* l) {
  __builtin_amdgcn_global_load_lds((as1_u32*)g, (as3_u32*)l, 16, 0, 0);
}

__device__ __forceinline__ unsigned short f2bf(float f) {
  union { float f; unsigned u; } v; v.f = f;
  unsigned r = v.u + 0x7FFFu + ((v.u >> 16) & 1u);   // RNE
  return (unsigned short)(r >> 16);
}
__device__ __forceinline__ float bf2f(unsigned short h) {
  union { unsigned u; float f; } v; v.u = ((unsigned)h) << 16;
  return v.f;
}
// packed bf16 convert: lo -> [15:0], hi -> [31:16], RNE
__device__ __forceinline__ unsigned cvtpk(float lo, float hi) {
  unsigned r;
  asm("v_cvt_pk_bf16_f32 %0, %1, %2" : "=v"(r) : "v"(lo), "v"(hi));
  return r;
}
// hardware 2^x (trans pipe, 1 op)
__device__ __forceinline__ float exp2h(float x) {
#if __has_builtin(__builtin_amdgcn_exp2f)
  return __builtin_amdgcn_exp2f(x);
#else
  float r; asm("v_exp_f32 %0, %1" : "=v"(r) : "v"(x)); return r;
#endif
}
// hardware reciprocal (trans pipe, 1 op) -- NOT the IEEE div sequence the
// compiler emits for `1.0f/x` without fast-math (that was ~10 VALU ops per
// sigmoid and the single largest VALU consumer in k_proj).
__device__ __forceinline__ float rcph(float x) {
#if __has_builtin(__builtin_amdgcn_rcpf)
  return __builtin_amdgcn_rcpf(x);
#else
  float r; asm("v_rcp_f32 %0, %1" : "=v"(r) : "v"(x)); return r;
#endif
}
// sigmoid(x) = 1/(1+exp(-x)) = rcp(1 + 2^(-x*log2e)):  mul, exp, add, rcp.
__device__ __forceinline__ float sigm(float x) {
  return rcph(1.0f + exp2h(x * -1.44269504f));
}

// a/b layout v3 (write-contiguous, read-gatherable):
//   element (i, k, c) lives at  i*131072 + (k>>5)*8192 + c*64 + (k&31)*2
// -> a k_proj block (one i, 128 consecutive k, all 128 c) writes ONE
//    contiguous 32 KB span.
// -> an einsum MFMA fragment (fixed c, 16 i, one 32-k chunk) = 16 x 64B rows
//    at 128 KB stride; global_load_lds's PER-LANE global source gathers it in
//    one instr (4 lanes per 64B row), landing in LDS in the fragment cell
//    order [irem][(k&31)*2].  LDS-side layout unchanged.

// ---------------------------------------------------------------------------
// K0: weights fp32 [c][o] -> bf16 transposed [o][c].  Order: ga,pa,gb,pb,go,po
// ---------------------------------------------------------------------------
__global__ void k_prep(const float* __restrict__ Wpa, const float* __restrict__ Wga,
                       const float* __restrict__ Wpb, const float* __restrict__ Wgb,
                       const float* __restrict__ Wgo, const float* __restrict__ Wpo,
                       unsigned short* __restrict__ Wt) {
  int t = blockIdx.x * blockDim.x + threadIdx.x;     // 0..98303
  int mat = t >> 14;
  int rem = t & 16383;
  int o = rem >> 7;
  int c = rem & 127;
  const float* src;
  switch (mat) {
    case 0: src = Wga; break;
    case 1: src = Wpa; break;
    case 2: src = Wgb; break;
    case 3: src = Wpb; break;
    case 4: src = Wgo; break;
    default: src = Wpo; break;
  }
  Wt[mat * 16384 + o * 128 + c] = f2bf(src[c * 128 + o]);
}

// ---------------------------------------------------------------------------
// K1 (fused LN + projections), weights-resident.  Per block: 128 flat positions
// (one z-row i, 128 consecutive k).  a/b stored in v3 layout.  Barrier-free
// after the LN sync.  rg loops unrolled x2 for cross-iteration ILP
// (ds_read/MFMA of iter n+1 overlaps the trans-heavy epilogue of iter n).
// ---------------------------------------------------------------------------
__global__ __launch_bounds__(256, 4) void k_proj(const float* __restrict__ z,
                                                 const float* __restrict__ lnw,
                                                 const float* __restrict__ lnb,
                                                 const unsigned short* __restrict__ Wt,
                                                 const int* __restrict__ maskp,
                                                 unsigned short* __restrict__ a_f,
                                                 unsigned short* __restrict__ b_f,
                                                 unsigned short* __restrict__ gout) {
  __shared__ __align__(16) unsigned char zbuf[128 * 272];   // rows padded 256->272B
  __shared__ float maskf[128];
  const int t = threadIdx.x;
  const int bid = blockIdx.x;
  const long r0 = (long)bid * 128;
  const int w = t >> 6, lane = t & 63;
  const int mn = lane & 15, q4 = lane >> 4;
  // layout constants for this block
  const int k0 = (bid & 3) * 128;          // first global k
  const long ibase = (long)(bid >> 2) * 131072;   // i * 128KB

  if (t < 128) maskf[t] = (float)maskp[r0 + t];

  // fused input LayerNorm: wave w owns rows w*32..w*32+31; 4 rows/iter,
  // lane holds 8 channels of one row (32B load); reduce over 16 lanes.
  {
    const int sub = lane >> 4, c16 = lane & 15;
    const float4 lw0 = ((const float4*)lnw)[c16 * 2];
    const float4 lw1 = ((const float4*)lnw)[c16 * 2 + 1];
    const float4 lb0 = ((const float4*)lnb)[c16 * 2];
    const float4 lb1 = ((const float4*)lnb)[c16 * 2 + 1];
#pragma unroll 2
    for (int rr = 0; rr < 8; ++rr) {
      const int row = w * 32 + rr * 4 + sub;
      const float4* zr = (const float4*)(z + (r0 + row) * 128);
      float4 v0 = zr[c16 * 2], v1 = zr[c16 * 2 + 1];
      float s = ((v0.x + v0.y) + (v0.z + v0.w)) + ((v1.x + v1.y) + (v1.z + v1.w));
      float q = v0.x * v0.x + v0.y * v0.y + v0.z * v0.z + v0.w * v0.w +
                v1.x * v1.x + v1.y * v1.y + v1.z * v1.z + v1.w * v1.w;
#pragma unroll
      for (int off = 8; off; off >>= 1) { s += __shfl_xor(s, off); q += __shfl_xor(q, off); }
      float mu = s * (1.0f / 128.0f);
      float rs = rsqrtf(q * (1.0f / 128.0f) - mu * mu + EPSV);
      uint4 o;
      o.x = cvtpk((v0.x - mu) * rs * lw0.x + lb0.x, (v0.y - mu) * rs * lw0.y + lb0.y);
      o.y = cvtpk((v0.z - mu) * rs * lw0.z + lb0.z, (v0.w - mu) * rs * lw0.w + lb0.w);
      o.z = cvtpk((v1.x - mu) * rs * lw1.x + lb1.x, (v1.y - mu) * rs * lw1.y + lb1.y);
      o.w = cvtpk((v1.z - mu) * rs * lw1.z + lb1.z, (v1.w - mu) * rs * lw1.w + lb1.w);
      *(uint4*)(&zbuf[row * 272 + c16 * 16]) = o;
    }
  }
  __syncthreads();
  // no further barriers: zbuf is read-only from here; waves free-run.

  // phases p=0 (a), p=1 (b): gate+proj weights resident in VGPRs
#pragma unroll 1
  for (int p = 0; p < 2; ++p) {
    const unsigned short* Wg = Wt + (p * 2) * 16384;
    const unsigned short* Wp = Wt + (p * 2 + 1) * 16384;
    unsigned short* dst = p ? b_f : a_f;
    bf16x8 wg[2][4], wp[2][4];
#pragma unroll
    for (int ntl = 0; ntl < 2; ++ntl)
#pragma unroll
      for (int kk = 0; kk < 4; ++kk) {
        const int o = (w * 2 + ntl) * 16 + mn;
        wg[ntl][kk] = *(const bf16x8*)(Wg + o * 128 + kk * 32 + q4 * 8);
        wp[ntl][kk] = *(const bf16x8*)(Wp + o * 128 + kk * 32 + q4 * 8);
      }
#pragma unroll 2
    for (int rg = 0; rg < 8; ++rg) {
      bf16x8 afr[4];
#pragma unroll
      for (int kk = 0; kk < 4; ++kk)
        afr[kk] = *(const bf16x8*)(&zbuf[(rg * 16 + mn) * 272 + kk * 64 + q4 * 16]);
      f32x4 aG[2] = {{0.f,0.f,0.f,0.f},{0.f,0.f,0.f,0.f}};
      f32x4 aP[2] = {{0.f,0.f,0.f,0.f},{0.f,0.f,0.f,0.f}};
#pragma unroll
      for (int kk = 0; kk < 4; ++kk)
#pragma unroll
        for (int ntl = 0; ntl < 2; ++ntl) {
          aG[ntl] = __builtin_amdgcn_mfma_f32_16x16x32_bf16(afr[kk], wg[ntl][kk], aG[ntl], 0, 0, 0);
          aP[ntl] = __builtin_amdgcn_mfma_f32_16x16x32_bf16(afr[kk], wp[ntl][kk], aP[ntl], 0, 0, 0);
        }
      const int rowb = rg * 16 + q4 * 4;        // k-offset within block (4 consec)
      const int kpos = k0 + rowb;               // global k of first element
      // v3 address: ibase + (kpos>>5)*8192 + c*64 + (kpos&31)*2
      char* dst0 = (char*)dst + ibase + (kpos >> 5) * 8192 + (kpos & 31) * 2;
#pragma unroll
      for (int ntl = 0; ntl < 2; ++ntl) {
        const int c = (w * 2 + ntl) * 16 + mn;
        float e0 = sigm(aG[ntl][0]) * aP[ntl][0] * maskf[rowb + 0];
        float e1 = sigm(aG[ntl][1]) * aP[ntl][1] * maskf[rowb + 1];
        float e2 = sigm(aG[ntl][2]) * aP[ntl][2] * maskf[rowb + 2];
        float e3 = sigm(aG[ntl][3]) * aP[ntl][3] * maskf[rowb + 3];
        uint2 pk;
        pk.x = cvtpk(e0, e1);
        pk.y = cvtpk(e2, e3);
        *(uint2*)(dst0 + c * 64) = pk;
      }
    }
  }

  {  // g phase: g = sigmoid(zln @ Wgo) -> gout[row][c] (block region is 64KB
     // contiguous; 2B stores merge in L2)
    const unsigned short* Wgp = Wt + 4 * 16384;
    bf16x8 wg[2][4];
#pragma unroll
    for (int ntl = 0; ntl < 2; ++ntl)
#pragma unroll
      for (int kk = 0; kk < 4; ++kk)
        wg[ntl][kk] = *(const bf16x8*)(Wgp + ((w * 2 + ntl) * 16 + mn) * 128 + kk * 32 + q4 * 8);
#pragma unroll 2
    for (int rg = 0; rg < 8; ++rg) {
      bf16x8 afr[4];
#pragma unroll
      for (int kk = 0; kk < 4; ++kk)
        afr[kk] = *(const bf16x8*)(&zbuf[(rg * 16 + mn) * 272 + kk * 64 + q4 * 16]);
      f32x4 aG[2] = {{0.f,0.f,0.f,0.f},{0.f,0.f,0.f,0.f}};
#pragma unroll
      for (int kk = 0; kk < 4; ++kk)
#pragma unroll
        for (int ntl = 0; ntl < 2; ++ntl)
          aG[ntl] = __builtin_amdgcn_mfma_f32_16x16x32_bf16(afr[kk], wg[ntl][kk], aG[ntl], 0, 0, 0);
      const int rowb = rg * 16 + q4 * 4;
#pragma unroll
      for (int ntl = 0; ntl < 2; ++ntl) {
        const int c = (w * 2 + ntl) * 16 + mn;
        unsigned u01 = cvtpk(sigm(aG[ntl][0]), sigm(aG[ntl][1]));
        unsigned u23 = cvtpk(sigm(aG[ntl][2]), sigm(aG[ntl][3]));
        gout[(r0 + rowb + 0) * 128 + c] = (unsigned short)u01;
        gout[(r0 + rowb + 1) * 128 + c] = (unsigned short)(u01 >> 16);
        gout[(r0 + rowb + 2) * 128 + c] = (unsigned short)u23;
        gout[(r0 + rowb + 3) * 128 + c] = (unsigned short)(u23 >> 16);
      }
    }
  }
}

// ---------------------------------------------------------------------------
// K3: per-channel GEMM  m_c = a_c @ b_c^T from v3-layout operands.
// 3-buffer counted-vmcnt pipeline.  Fragment staging: one stage16 per frag,
// PER-LANE gather (lane l -> row i = f*16 + (l>>2), byte (l&3)*16 of the
// (i,kc,ch) 64B row) -> LDS lands lane-linear in the fragment cell order, so
// ds_read/MFMA mapping is unchanged.  A frags reused x4 by same-XCD siblings.
// ---------------------------------------------------------------------------
__global__ __launch_bounds__(256, 3) void k_einsum(const unsigned short* __restrict__ af_g,
                                                   const unsigned short* __restrict__ bf_g,
                                                   unsigned short* __restrict__ m_t) {
  __shared__ __align__(16) unsigned char shm[49152];  // 3 x 16KB stage; epilogue reuses
  const int t = threadIdx.x;
  const int w = t >> 6, lane = t & 63;
  const int bid = blockIdx.x;
  const int xcd = bid & 7;               // round-robin bid%8 -> XCD
  const int j = bid >> 3;
  const int ch = xcd * 16 + (j >> 4);    // 16 channels per XCD
  const int tile = j & 15;
  const int ti = tile >> 2, tj = tile & 3;
  const int wr = w >> 1, wc = w & 1;
  const int mn = lane & 15, q4 = lane >> 4;
  const int loff = (mn * 4 + q4) * 16;   // cell order: (i&15)*4 + k-subchunk

  // per-lane gather component: row (l>>2) of the 16-row frag, 16B piece (l&3)
  const long lanepart = (long)(lane >> 2) * 131072 + (lane & 3) * 16 + ch * 64;

  // wave w stages fragments f = w*4 .. w*4+3  (f<8: A frag ti*8+f, else B frag)
  const char* gsrc[4];
#pragma unroll
  for (int u = 0; u < 4; ++u) {
    const int f = w * 4 + u;
    gsrc[u] = (f < 8)
        ? (const char*)af_g + (long)(ti * 8 + f) * 16 * 131072 + lanepart
        : (const char*)bf_g + (long)(tj * 8 + (f - 8)) * 16 * 131072 + lanepart;
  }

  f32x4 acc[4][4];
#pragma unroll
  for (int i = 0; i < 4; ++i)
#pragma unroll
    for (int jj = 0; jj < 4; ++jj) acc[i][jj] = (f32x4){0.f, 0.f, 0.f, 0.f};

#define STAGE(q, k32)                                                          \
  {                                                                            \
    _Pragma("unroll")                                                          \
    for (int u = 0; u < 4; ++u)                                                \
      stage16(gsrc[u] + (long)(k32) * 8192,                                    \
              &shm[(q) * 16384 + (w * 4 + u) * 1024]);                         \
  }

  STAGE(0, 0)
  STAGE(1, 1)
#pragma unroll 1
  for (int k32 = 0; k32 < 16; ++k32) {
    if (k32 < 15) {
      // buf k resident when only the newest 4 (buf k+1's) remain outstanding
      asm volatile("s_waitcnt vmcnt(4)\n\ts_barrier" ::: "memory");
    } else {
      asm volatile("s_waitcnt vmcnt(0)\n\ts_barrier" ::: "memory");
    }
    if (k32 + 2 < 16) STAGE((k32 + 2) % 3, k32 + 2)   // overwrite buf (k-1): safe
    const int cb = (k32 % 3) * 16384;
    bf16x8 afr[4], bfr[4];
#pragma unroll
    for (int mt = 0; mt < 4; ++mt)
      afr[mt] = *(const bf16x8*)(&shm[cb + (wr * 4 + mt) * 1024 + loff]);
#pragma unroll
    for (int nt = 0; nt < 4; ++nt)
      bfr[nt] = *(const bf16x8*)(&shm[cb + 8192 + (wc * 4 + nt) * 1024 + loff]);
#pragma unroll
    for (int mt = 0; mt < 4; ++mt)
#pragma unroll
      for (int nt = 0; nt < 4; ++nt)
        acc[mt][nt] = __builtin_amdgcn_mfma_f32_16x16x32_bf16(
            afr[mt], bfr[nt], acc[mt][nt], 0, 0, 0);
  }
#undef STAGE
  __syncthreads();   // all waves done reading stage buffers before eb reuse

  // epilogue: per-wave LDS bounce (rows padded to 144B), coalesced bf16 store.
  unsigned char* eb = shm + w * 9216;
#pragma unroll
  for (int mt = 0; mt < 4; ++mt)
#pragma unroll
    for (int nt = 0; nt < 4; ++nt) {
      const int rlb = mt * 16 + q4 * 4;
      const int cl = nt * 16 + mn;
      unsigned u01 = cvtpk(acc[mt][nt][0], acc[mt][nt][1]);
      unsigned u23 = cvtpk(acc[mt][nt][2], acc[mt][nt][3]);
      *(unsigned short*)(&eb[(rlb + 0) * 144 + cl * 2]) = (unsigned short)u01;
      *(unsigned short*)(&eb[(rlb + 1) * 144 + cl * 2]) = (unsigned short)(u01 >> 16);
      *(unsigned short*)(&eb[(rlb + 2) * 144 + cl * 2]) = (unsigned short)u23;
      *(unsigned short*)(&eb[(rlb + 3) * 144 + cl * 2]) = (unsigned short)(u23 >> 16);
    }
  char* Mg = (char*)m_t + (long)ch * 524288 +
             (long)(ti * 128 + wr * 64) * 1024 + (tj * 128 + wc * 64) * 2;
#pragma unroll
  for (int it = 0; it < 8; ++it) {
    int rl = it * 8 + (lane >> 3), cc = lane & 7;
    *(int4*)(Mg + (long)rl * 1024 + cc * 16) = *(const int4*)(&eb[rl * 144 + cc * 16]);
  }
}

// ---------------------------------------------------------------------------
// K4: per 64-row tile: LN(m) over c, m_ln @ Wpo, * g * mask -> dz fp32
// v2: g staged into LDS up front (coalesced); fp32 obuf LDS bounce REMOVED --
// GEMM epilogue multiplies acc * g * mask in registers and stores directly.
// One less barrier, LDS 52->36 KB (4 blocks/CU).
// ---------------------------------------------------------------------------
__global__ __launch_bounds__(256, 4) void k_out(const unsigned short* __restrict__ m_t,
                                                const unsigned short* __restrict__ gbuf,
                                                const unsigned short* __restrict__ Wt,
                                                const int* __restrict__ maskp,
                                                const float* __restrict__ lnw,
                                                const float* __restrict__ lnb,
                                                float* __restrict__ out) {
  __shared__ unsigned char mln[64 * 272];   // [row][c] bf16, padded rows
  __shared__ unsigned char glds[64 * 272];  // [row][c] g bf16, padded rows
  __shared__ float lw[128], lb[128], mk[64];
  const int t = threadIdx.x;
  const long r0 = (long)blockIdx.x * 64;

  // stage + transpose m tile: m_t[c][r0+..] -> mln[row][c], e-rotated
#pragma unroll
  for (int it = 0; it < 4; ++it) {
    int chunk = it * 256 + t;
    int c = chunk >> 3, cc = chunk & 7;
    int4 rv = *(const int4*)((const char*)m_t + (long)c * 524288 + r0 * 2 + cc * 16);
    const unsigned short* rp = (const unsigned short*)&rv;
#pragma unroll
    for (int e = 0; e < 8; ++e) {
      int er = (e + cc) & 7;   // rotate: rows mod 8 distinct across lanes
      *(unsigned short*)(&mln[(cc * 8 + er) * 272 + c * 2]) = rp[er];
    }
  }
  // stage g rows coalesced: 64 rows x 256B
#pragma unroll
  for (int it = 0; it < 4; ++it) {
    int chunk = it * 256 + t;
    int row = chunk >> 4, cc = chunk & 15;
    *(int4*)(&glds[row * 272 + cc * 16]) =
        *(const int4*)((const char*)gbuf + (r0 + row) * 256 + cc * 16);
  }
  if (t < 128) { lw[t] = lnw[t]; lb[t] = lnb[t]; }
  if (t < 64) mk[t] = (float)maskp[r0 + t];
  __syncthreads();

  {  // LayerNorm over c: 4 threads per row; write m_ln back in place (bf16)
    int row = t >> 2, part = t & 3;
    float xv[32];
    float s = 0.f, q = 0.f;
#pragma unroll
    for (int jj = 0; jj < 16; ++jj) {
      unsigned u = *(const unsigned*)(&mln[row * 272 + part * 64 + jj * 4]);
      float x0 = bf2f((unsigned short)(u & 0xffff));
      float x1 = bf2f((unsigned short)(u >> 16));
      xv[2 * jj] = x0; xv[2 * jj + 1] = x1;
      s += x0 + x1; q += x0 * x0 + x1 * x1;
    }
    s += __shfl_xor(s, 1); q += __shfl_xor(q, 1);
    s += __shfl_xor(s, 2); q += __shfl_xor(q, 2);
    float mu = s * (1.f / 128.f);
    float var = q * (1.f / 128.f) - mu * mu;
    float rs = rsqrtf(var + EPSV);
#pragma unroll
    for (int jj = 0; jj < 16; ++jj) {
      int c = part * 32 + 2 * jj;
      unsigned pk = cvtpk((xv[2 * jj] - mu) * rs * lw[c] + lb[c],
                          (xv[2 * jj + 1] - mu) * rs * lw[c + 1] + lb[c + 1]);
      *(unsigned*)(&mln[row * 272 + c * 2]) = pk;
    }
  }
  __syncthreads();

  // GEMM: m_ln @ Wpo; epilogue applies g * mask and stores directly
  const int w = t >> 6, lane = t & 63;
  const int mn = lane & 15, q4 = lane >> 4;
  bf16x8 afr[4];
#pragma unroll
  for (int kk = 0; kk < 4; ++kk)
    afr[kk] = *(const bf16x8*)(&mln[(w * 16 + mn) * 272 + kk * 64 + q4 * 16]);
  const unsigned short* Wp = Wt + 5 * 16384;
#pragma unroll 1
  for (int nt = 0; nt < 8; ++nt) {
    f32x4 acc = {0.f, 0.f, 0.f, 0.f};
#pragma unroll
    for (int kk = 0; kk < 4; ++kk) {
      bf16x8 bfr = *(const bf16x8*)(Wp + (nt * 16 + mn) * 128 + kk * 32 + q4 * 8);
      acc = __builtin_amdgcn_mfma_f32_16x16x32_bf16(afr[kk], bfr, acc, 0, 0, 0);
    }
    const int cl = nt * 16 + mn;
#pragma unroll
    for (int r = 0; r < 4; ++r) {
      const int row = w * 16 + q4 * 4 + r;
      float gv = bf2f(*(const unsigned short*)(&glds[row * 272 + cl * 2]));
      out[(r0 + row) * 128 + cl] = acc[r] * gv * mk[row];
    }
  }
}

// ---------------------------------------------------------------------------
extern "C" void kernel_launch(void* const* d_in, const int* in_sizes, int n_in,
                              void* d_out, int out_size, void* d_ws, size_t ws_size,
                              hipStream_t stream) {
  const float* z    = (const float*)d_in[0];
  const int* maskp  = (const int*)d_in[1];
  const float* lniw = (const float*)d_in[2];
  const float* lnib = (const float*)d_in[3];
  const float* lnow = (const float*)d_in[4];
  const float* lnob = (const float*)d_in[5];
  const float* Wpa  = (const float*)d_in[6];
  const float* Wga  = (const float*)d_in[7];
  const float* Wpb  = (const float*)d_in[8];
  const float* Wgb  = (const float*)d_in[9];
  const float* Wgo  = (const float*)d_in[10];
  const float* Wpo  = (const float*)d_in[11];
  float* out = (float*)d_out;

  char* ws = (char*)d_ws;
  unsigned short* a_f = (unsigned short*)(ws);                 // bf16 v3 layout, 64 MiB
  unsigned short* b_f = (unsigned short*)(ws + 67108864);      // bf16 v3 layout
  unsigned short* g   = (unsigned short*)(ws + 134217728);     // bf16 [262144][128]
  unsigned short* m_t = (unsigned short*)(ws + 201326592);     // bf16 [128][262144]
  unsigned short* Wt  = (unsigned short*)(ws + 268435456);     // 6 x [128][128] bf16

  k_prep<<<384, 256, 0, stream>>>(Wpa, Wga, Wpb, Wgb, Wgo, Wpo, Wt);
  k_proj<<<2048, 256, 0, stream>>>(z, lniw, lnib, Wt, maskp, a_f, b_f, g);
  k_einsum<<<2048, 256, 0, stream>>>(a_f, b_f, m_t);
  k_out<<<4096, 256, 0, stream>>>(m_t, g, Wt, maskp, lnow, lnob, out);
}